// Round 1
// baseline (581.089 us; speedup 1.0000x reference)
//
#include <hip/hip_runtime.h>
#include <hip/hip_bf16.h>
#include <cstdint>

#define HID    1024
#define MID    512
#define NEXP   16
#define NTOKS  2048
#define TOPKE  4
#define RSCALE 2.5f

typedef __attribute__((ext_vector_type(8))) short bf16x8;
typedef __attribute__((ext_vector_type(4))) float f32x4;

__device__ __forceinline__ ushort f2bf(float f){
  unsigned u = __float_as_uint(f);
  u += 0x7fffu + ((u >> 16) & 1u);
  return (ushort)(u >> 16);
}
__device__ __forceinline__ float bf2f(ushort h){ return __uint_as_float(((unsigned)h) << 16); }

// ---------------- gating ----------------
__global__ __launch_bounds__(64) void k_gate(const float* __restrict__ x,
                                             const float* __restrict__ gk,
                                             const float* __restrict__ gb,
                                             int* __restrict__ counts,
                                             int* __restrict__ tidx,
                                             float* __restrict__ tw)
{
  const int t = blockIdx.x;
  const int l = threadIdx.x;
  float acc[NEXP];
  #pragma unroll
  for (int e = 0; e < NEXP; ++e) acc[e] = 0.f;
  const float* xr = x + (size_t)t * HID;
  for (int h = l; h < HID; h += 64){
    float xv = xr[h];
    const f32x4* g4 = reinterpret_cast<const f32x4*>(gk + (size_t)h * NEXP);
    #pragma unroll
    for (int q = 0; q < 4; ++q){
      f32x4 g = g4[q];
      acc[q*4+0] += xv * g[0];
      acc[q*4+1] += xv * g[1];
      acc[q*4+2] += xv * g[2];
      acc[q*4+3] += xv * g[3];
    }
  }
  #pragma unroll
  for (int e = 0; e < NEXP; ++e){
    #pragma unroll
    for (int off = 32; off > 0; off >>= 1)
      acc[e] += __shfl_xor(acc[e], off, 64);
  }
  if (l == 0){
    float s4[NEXP];
    #pragma unroll
    for (int e = 0; e < NEXP; ++e){
      float sc = 1.f / (1.f + expf(-acc[e]));
      s4[e] = sc + gb[e];
    }
    // group scores: sum of top-2 in each group of 4
    float gs[4];
    #pragma unroll
    for (int g = 0; g < 4; ++g){
      float m1 = -1e30f, m2 = -1e30f;
      #pragma unroll
      for (int j = 0; j < 4; ++j){
        float v = s4[g*4+j];
        if (v > m1){ m2 = m1; m1 = v; } else if (v > m2){ m2 = v; }
      }
      gs[g] = m1 + m2;
    }
    // top-2 groups (stable: earliest index on tie)
    int g1 = 0;
    for (int g = 1; g < 4; ++g) if (gs[g] > gs[g1]) g1 = g;
    int g2 = -1;
    for (int g = 0; g < 4; ++g){
      if (g == g1) continue;
      if (g2 < 0 || gs[g] > gs[g2]) g2 = g;
    }
    float ms[NEXP];
    #pragma unroll
    for (int e = 0; e < NEXP; ++e){
      int g = e >> 2;
      ms[e] = (g == g1 || g == g2) ? s4[e] : 0.0f;
    }
    // stable top-4 over masked scores (zeros are candidates, like jax)
    bool used[NEXP];
    #pragma unroll
    for (int e = 0; e < NEXP; ++e) used[e] = false;
    int sel[TOPKE]; float val[TOPKE]; float denom = 0.f;
    #pragma unroll
    for (int k = 0; k < TOPKE; ++k){
      int be = -1; float bv = -1e30f;
      for (int e = 0; e < NEXP; ++e){
        if (used[e]) continue;
        if (ms[e] > bv){ bv = ms[e]; be = e; }
      }
      used[be] = true; sel[k] = be; val[k] = bv; denom += bv;
    }
    float inv = RSCALE / (denom + 1e-20f);
    #pragma unroll
    for (int k = 0; k < TOPKE; ++k){
      tidx[t*TOPKE + k] = sel[k];
      tw  [t*TOPKE + k] = val[k] * inv;
      atomicAdd(&counts[sel[k]], 1);
    }
  }
}

__global__ void k_scan(const int* __restrict__ counts, int* __restrict__ offs,
                       int* __restrict__ cursor)
{
  if (threadIdx.x == 0){
    int s = 0;
    for (int e = 0; e < NEXP; ++e){ offs[e] = s; s += counts[e]; }
    offs[NEXP] = s;
  }
  if (threadIdx.x < NEXP) cursor[threadIdx.x] = 0;
}

__global__ __launch_bounds__(256) void k_place(const int* __restrict__ tidx,
                                               const float* __restrict__ tw,
                                               const int* __restrict__ offs,
                                               int* __restrict__ cursor,
                                               int* __restrict__ tlist,
                                               float* __restrict__ wlist)
{
  int t = blockIdx.x * 256 + threadIdx.x;
  if (t >= NTOKS) return;
  #pragma unroll
  for (int k = 0; k < TOPKE; ++k){
    int e = tidx[t*TOPKE + k];
    int slot = atomicAdd(&cursor[e], 1);
    int p = offs[e] + slot;
    tlist[p] = t;
    wlist[p] = tw[t*TOPKE + k];
  }
}

// ---------------- tiled bf16 MFMA GEMM ----------------
// MODE 0: shared gate : A=x fp32 direct,   out bf16 g_s
// MODE 1: shared up   : A=x fp32 direct,   out bf16 i_s = silu(g_s)*acc
// MODE 2: routed gate : A=x fp32 gathered, out bf16 g_r (assignment rows)
// MODE 3: routed up   : A=x fp32 gathered, out bf16 i_r = silu(g_r)*acc
// MODE 4: shared down : A=i_s bf16 direct, out fp32 store to d_out
// MODE 5: routed down : A=i_r bf16 rows,   atomicAdd w*acc into d_out
template<int MODE>
__global__ __launch_bounds__(256) void k_gemm(
    const float* __restrict__ Af, const ushort* __restrict__ Ab,
    const float* __restrict__ B,
    ushort* __restrict__ Obf, float* __restrict__ Ofp,
    const ushort* __restrict__ Gbuf,
    const int* __restrict__ counts, const int* __restrict__ offs,
    const int* __restrict__ tlist, const float* __restrict__ wlist,
    int K, int N)
{
  constexpr bool ROUTED = (MODE == 2 || MODE == 3 || MODE == 5);
  constexpr bool A_BF16 = (MODE == 4 || MODE == 5);
  constexpr bool GATHER = (MODE == 2 || MODE == 3);

  __shared__ ushort As[128 * 40];
  __shared__ ushort Bs[128 * 40];

  const int e = ROUTED ? blockIdx.z : 0;
  const int mbase = blockIdx.y * 128;
  const int nbase = blockIdx.x * 128;
  int cnt = NTOKS, aoff = 0;
  if constexpr (ROUTED){
    cnt = counts[e];
    if (mbase >= cnt) return;
    aoff = offs[e];
  }
  const float* Bb = B + (size_t)e * K * N;

  const int tid  = threadIdx.x;
  const int lane = tid & 63;
  const int wid  = tid >> 6;
  const int wm = wid >> 1, wn = wid & 1;

  const int tdiv8 = tid >> 3;        // 0..31
  const int k4    = (tid & 7) * 4;   // 0..28 (A k-offset)
  const int kg    = tid & 7;         // B k-group
  const int ng    = tid >> 3;        // B n-group 0..31

  int agrow[4]; bool avalid[4];
  #pragma unroll
  for (int it = 0; it < 4; ++it){
    int r = it * 32 + tdiv8;
    int ar = mbase + r;
    if constexpr (GATHER){
      avalid[it] = (ar < cnt);
      agrow[it]  = avalid[it] ? tlist[aoff + ar] : 0;
    } else if constexpr (MODE == 5){
      avalid[it] = (ar < cnt);
      agrow[it]  = aoff + ar;
    } else {
      avalid[it] = true;
      agrow[it]  = ar;
    }
  }

  f32x4 acc[4][4];
  #pragma unroll
  for (int i = 0; i < 4; ++i)
    #pragma unroll
    for (int j = 0; j < 4; ++j)
      acc[i][j] = (f32x4){0.f, 0.f, 0.f, 0.f};

  const int nk = K >> 5;
  for (int kt = 0; kt < nk; ++kt){
    const int kg0 = kt << 5;
    // stage A: As[r][k] (bf16), pad 40
    #pragma unroll
    for (int it = 0; it < 4; ++it){
      int r = it * 32 + tdiv8;
      ushort4 wv;
      if constexpr (A_BF16){
        if (avalid[it]) wv = *reinterpret_cast<const ushort4*>(Ab + (size_t)agrow[it] * K + kg0 + k4);
        else wv = make_ushort4(0, 0, 0, 0);
      } else {
        if (avalid[it]){
          f32x4 f = *reinterpret_cast<const f32x4*>(Af + (size_t)agrow[it] * K + kg0 + k4);
          wv = make_ushort4(f2bf(f[0]), f2bf(f[1]), f2bf(f[2]), f2bf(f[3]));
        } else wv = make_ushort4(0, 0, 0, 0);
      }
      *reinterpret_cast<ushort4*>(&As[r * 40 + k4]) = wv;
    }
    // stage B transposed: Bs[n][k] = bf16(B[kg0+k][nbase+n])
    {
      f32x4 rr[4];
      #pragma unroll
      for (int dk = 0; dk < 4; ++dk)
        rr[dk] = *reinterpret_cast<const f32x4*>(Bb + (size_t)(kg0 + 4*kg + dk) * N + nbase + 4*ng);
      #pragma unroll
      for (int i = 0; i < 4; ++i){
        ushort4 wv = make_ushort4(f2bf(rr[0][i]), f2bf(rr[1][i]), f2bf(rr[2][i]), f2bf(rr[3][i]));
        *reinterpret_cast<ushort4*>(&Bs[(4*ng + i) * 40 + 4*kg]) = wv;
      }
    }
    __syncthreads();
    const int kfo = (lane >> 4) * 8;  // element offset in row
    const int fr  = lane & 15;
    bf16x8 afr[4], bfr[4];
    #pragma unroll
    for (int mf = 0; mf < 4; ++mf)
      afr[mf] = *reinterpret_cast<const bf16x8*>(&As[(wm*64 + mf*16 + fr) * 40 + kfo]);
    #pragma unroll
    for (int nf = 0; nf < 4; ++nf)
      bfr[nf] = *reinterpret_cast<const bf16x8*>(&Bs[(wn*64 + nf*16 + fr) * 40 + kfo]);
    #pragma unroll
    for (int mf = 0; mf < 4; ++mf)
      #pragma unroll
      for (int nf = 0; nf < 4; ++nf)
        acc[mf][nf] = __builtin_amdgcn_mfma_f32_16x16x32_bf16(afr[mf], bfr[nf], acc[mf][nf], 0, 0, 0);
    __syncthreads();
  }

  // epilogue: C/D mapping col = lane&15, row = (lane>>4)*4 + reg
  const int ccol = lane & 15;
  const int crow = (lane >> 4) * 4;
  #pragma unroll
  for (int mf = 0; mf < 4; ++mf){
    #pragma unroll
    for (int nf = 0; nf < 4; ++nf){
      #pragma unroll
      for (int r = 0; r < 4; ++r){
        float v = acc[mf][nf][r];
        int rt = wm*64 + mf*16 + crow + r;
        int ct = wn*64 + nf*16 + ccol;
        int ar = mbase + rt;
        int gcol = nbase + ct;
        if constexpr (MODE == 0 || MODE == 2){
          if (!ROUTED || ar < cnt){
            size_t orow = ROUTED ? (size_t)(aoff + ar) : (size_t)ar;
            Obf[orow * N + gcol] = f2bf(v);
          }
        } else if constexpr (MODE == 1 || MODE == 3){
          if (!ROUTED || ar < cnt){
            size_t orow = ROUTED ? (size_t)(aoff + ar) : (size_t)ar;
            float g = bf2f(Gbuf[orow * N + gcol]);
            float s = g / (1.f + expf(-g));
            Obf[orow * N + gcol] = f2bf(s * v);
          }
        } else if constexpr (MODE == 4){
          Ofp[(size_t)ar * N + gcol] = v;
        } else {
          if (ar < cnt){
            int arow = aoff + ar;
            int tok  = tlist[arow];
            float w  = wlist[arow];
            atomicAdd(&Ofp[(size_t)tok * N + gcol], w * v);
          }
        }
      }
    }
  }
}

// ---------------- launcher ----------------
extern "C" void kernel_launch(void* const* d_in, const int* in_sizes, int n_in,
                              void* d_out, int out_size, void* d_ws, size_t ws_size,
                              hipStream_t stream)
{
  const float* x   = (const float*)d_in[0];
  const float* gk  = (const float*)d_in[1];
  const float* gb  = (const float*)d_in[2];
  const float* wg  = (const float*)d_in[3];
  const float* wu  = (const float*)d_in[4];
  const float* wd  = (const float*)d_in[5];
  const float* swg = (const float*)d_in[6];
  const float* swu = (const float*)d_in[7];
  const float* swd = (const float*)d_in[8];
  float* out = (float*)d_out;
  char* ws = (char*)d_ws;

  int*    counts = (int*)(ws + 0);
  int*    cursor = (int*)(ws + 64);
  int*    offs   = (int*)(ws + 128);
  int*    tidx   = (int*)(ws + 4096);
  float*  tw     = (float*)(ws + 36864);
  int*    tlist  = (int*)(ws + 69632);
  float*  wlist  = (float*)(ws + 102400);
  ushort* g_s    = (ushort*)(ws + (2ull  << 20));  // [2048][1024] bf16
  ushort* i_s    = (ushort*)(ws + (6ull  << 20));  // [2048][1024] bf16
  ushort* g_r    = (ushort*)(ws + (10ull << 20));  // [8192][512]  bf16
  ushort* i_r    = (ushort*)(ws + (18ull << 20));  // [8192][512]  bf16

  hipMemsetAsync(counts, 0, 64, stream);
  k_gate<<<NTOKS, 64, 0, stream>>>(x, gk, gb, counts, tidx, tw);
  k_scan<<<1, 64, 0, stream>>>(counts, offs, cursor);
  k_place<<<NTOKS/256, 256, 0, stream>>>(tidx, tw, offs, cursor, tlist, wlist);

  // shared expert: g = x@swg ; i = silu(g)*(x@swu) ; out = i@swd (plain store)
  k_gemm<0><<<dim3(8, 16, 1),  256, 0, stream>>>(x, nullptr, swg, g_s, nullptr, nullptr,
                                                 counts, offs, tlist, wlist, 1024, 1024);
  k_gemm<1><<<dim3(8, 16, 1),  256, 0, stream>>>(x, nullptr, swu, i_s, nullptr, g_s,
                                                 counts, offs, tlist, wlist, 1024, 1024);
  // routed experts (token-gathered): g_r, i_r, then scatter-add down-proj
  k_gemm<2><<<dim3(4, 16, 16), 256, 0, stream>>>(x, nullptr, wg, g_r, nullptr, nullptr,
                                                 counts, offs, tlist, wlist, 1024, 512);
  k_gemm<3><<<dim3(4, 16, 16), 256, 0, stream>>>(x, nullptr, wu, i_r, nullptr, g_r,
                                                 counts, offs, tlist, wlist, 1024, 512);
  k_gemm<4><<<dim3(8, 16, 1),  256, 0, stream>>>(nullptr, i_s, swd, nullptr, out, nullptr,
                                                 counts, offs, tlist, wlist, 1024, 1024);
  k_gemm<5><<<dim3(8, 16, 16), 256, 0, stream>>>(nullptr, i_r, wd, nullptr, out, nullptr,
                                                 counts, offs, tlist, wlist, 512, 1024);
}

// Round 2
// 308.691 us; speedup vs baseline: 1.8824x; 1.8824x over previous
//
#include <hip/hip_runtime.h>
#include <hip/hip_bf16.h>
#include <cstdint>

#define HID    1024
#define MID    512
#define NEXP   16
#define NTOKS  2048
#define TOPKE  4
#define RSCALE 2.5f

typedef __attribute__((ext_vector_type(8))) short  bf16x8;
typedef __attribute__((ext_vector_type(8))) ushort u16x8;
typedef __attribute__((ext_vector_type(4))) float  f32x4;

__device__ __forceinline__ ushort f2bf(float f){
  unsigned u = __float_as_uint(f);
  u += 0x7fffu + ((u >> 16) & 1u);
  return (ushort)(u >> 16);
}
__device__ __forceinline__ float bf2f(ushort h){ return __uint_as_float(((unsigned)h) << 16); }

#define GLD16(g, l) __builtin_amdgcn_global_load_lds( \
    (const __attribute__((address_space(1))) unsigned int*)(g), \
    (__attribute__((address_space(3))) unsigned int*)(l), 16, 0, 0)

// ---------------- gating ----------------
__global__ __launch_bounds__(64) void k_gate(const float* __restrict__ x,
                                             const float* __restrict__ gk,
                                             const float* __restrict__ gb,
                                             int* __restrict__ counts,
                                             int* __restrict__ tidx,
                                             float* __restrict__ tw)
{
  const int t = blockIdx.x;
  const int l = threadIdx.x;
  float acc[NEXP];
  #pragma unroll
  for (int e = 0; e < NEXP; ++e) acc[e] = 0.f;
  const float* xr = x + (size_t)t * HID;
  for (int h = l; h < HID; h += 64){
    float xv = xr[h];
    const f32x4* g4 = reinterpret_cast<const f32x4*>(gk + (size_t)h * NEXP);
    #pragma unroll
    for (int q = 0; q < 4; ++q){
      f32x4 g = g4[q];
      acc[q*4+0] += xv * g[0];
      acc[q*4+1] += xv * g[1];
      acc[q*4+2] += xv * g[2];
      acc[q*4+3] += xv * g[3];
    }
  }
  #pragma unroll
  for (int e = 0; e < NEXP; ++e){
    #pragma unroll
    for (int off = 32; off > 0; off >>= 1)
      acc[e] += __shfl_xor(acc[e], off, 64);
  }
  if (l == 0){
    float s4[NEXP];
    #pragma unroll
    for (int e = 0; e < NEXP; ++e){
      float sc = 1.f / (1.f + expf(-acc[e]));
      s4[e] = sc + gb[e];
    }
    float gs[4];
    #pragma unroll
    for (int g = 0; g < 4; ++g){
      float m1 = -1e30f, m2 = -1e30f;
      #pragma unroll
      for (int j = 0; j < 4; ++j){
        float v = s4[g*4+j];
        if (v > m1){ m2 = m1; m1 = v; } else if (v > m2){ m2 = v; }
      }
      gs[g] = m1 + m2;
    }
    int g1 = 0;
    for (int g = 1; g < 4; ++g) if (gs[g] > gs[g1]) g1 = g;
    int g2 = -1;
    for (int g = 0; g < 4; ++g){
      if (g == g1) continue;
      if (g2 < 0 || gs[g] > gs[g2]) g2 = g;
    }
    float ms[NEXP];
    #pragma unroll
    for (int e = 0; e < NEXP; ++e){
      int g = e >> 2;
      ms[e] = (g == g1 || g == g2) ? s4[e] : 0.0f;
    }
    bool used[NEXP];
    #pragma unroll
    for (int e = 0; e < NEXP; ++e) used[e] = false;
    int sel[TOPKE]; float val[TOPKE]; float denom = 0.f;
    #pragma unroll
    for (int k = 0; k < TOPKE; ++k){
      int be = -1; float bv = -1e30f;
      for (int e = 0; e < NEXP; ++e){
        if (used[e]) continue;
        if (ms[e] > bv){ bv = ms[e]; be = e; }
      }
      used[be] = true; sel[k] = be; val[k] = bv; denom += bv;
    }
    float inv = RSCALE / (denom + 1e-20f);
    #pragma unroll
    for (int k = 0; k < TOPKE; ++k){
      tidx[t*TOPKE + k] = sel[k];
      tw  [t*TOPKE + k] = val[k] * inv;
      atomicAdd(&counts[sel[k]], 1);
    }
  }
}

__global__ void k_scan(const int* __restrict__ counts, int* __restrict__ offs,
                       int* __restrict__ cursor)
{
  if (threadIdx.x == 0){
    int s = 0;
    for (int e = 0; e < NEXP; ++e){ offs[e] = s; s += counts[e]; }
    offs[NEXP] = s;
  }
  if (threadIdx.x < NEXP) cursor[threadIdx.x] = 0;
}

__global__ __launch_bounds__(256) void k_place(const int* __restrict__ tidx,
                                               const float* __restrict__ tw,
                                               const int* __restrict__ offs,
                                               int* __restrict__ cursor,
                                               int* __restrict__ tlist,
                                               float* __restrict__ wlist)
{
  int t = blockIdx.x * 256 + threadIdx.x;
  if (t >= NTOKS) return;
  #pragma unroll
  for (int k = 0; k < TOPKE; ++k){
    int e = tidx[t*TOPKE + k];
    int slot = atomicAdd(&cursor[e], 1);
    int p = offs[e] + slot;
    tlist[p] = t;
    wlist[p] = tw[t*TOPKE + k];
  }
}

// ---------------- prep: fp32 -> bf16 convert ----------------
__global__ __launch_bounds__(256) void k_cvt(const float* __restrict__ in,
                                             ushort* __restrict__ out, int n8)
{
  int i = blockIdx.x * 256 + threadIdx.x;
  if (i >= n8) return;
  f32x4 a = *reinterpret_cast<const f32x4*>(in + (size_t)i*8);
  f32x4 b = *reinterpret_cast<const f32x4*>(in + (size_t)i*8 + 4);
  u16x8 o;
  o[0]=f2bf(a[0]); o[1]=f2bf(a[1]); o[2]=f2bf(a[2]); o[3]=f2bf(a[3]);
  o[4]=f2bf(b[0]); o[5]=f2bf(b[1]); o[6]=f2bf(b[2]); o[7]=f2bf(b[3]);
  *reinterpret_cast<u16x8*>(out + (size_t)i*8) = o;
}

// ---------------- prep: fp32 [K][N] -> bf16 [N][K] transpose ----------------
__global__ __launch_bounds__(256) void k_tr(const float* __restrict__ in,
                                            ushort* __restrict__ out, int K, int N)
{
  const int e = blockIdx.z;
  in  += (size_t)e * K * N;
  out += (size_t)e * K * N;
  const int kb = blockIdx.y * 64, nb = blockIdx.x * 64;
  __shared__ ushort T[64 * 68];
  const int t = threadIdx.x;
  const int r = t >> 4, c4 = (t & 15) * 4;
  #pragma unroll
  for (int i = 0; i < 4; ++i){
    f32x4 v = *reinterpret_cast<const f32x4*>(in + (size_t)(kb + r + i*16) * N + nb + c4);
    #pragma unroll
    for (int j = 0; j < 4; ++j)
      T[(c4 + j) * 68 + r + i*16] = f2bf(v[j]);   // T[n_local][k_local]
  }
  __syncthreads();
  #pragma unroll
  for (int i = 0; i < 4; ++i){
    int n = r + i*16;
    ushort4 o = *reinterpret_cast<const ushort4*>(&T[n * 68 + c4]);
    *reinterpret_cast<ushort4*>(out + (size_t)(nb + n) * K + kb + c4) = o;
  }
}

// ---------------- mega GEMM (m97 structure) ----------------
// 128x128 tile, BK=64, 256 threads (2x2 waves of 64x64), global_load_lds(16B)
// with inverse-swizzled per-lane source; frag reads XOR-swizzled (row&7)<<4.
// PHASE 0: gate/up. z: 0=shared-gate 1=shared-up 2+e=routed-gate 18+e=routed-up
// PHASE 1: down.    z: 0=shared-down  1+e=routed-down (atomicAdd into out)
template<int PHASE>
__global__ __launch_bounds__(256) void k_mm(
    const ushort* __restrict__ xb,
    const ushort* __restrict__ i_s,  const ushort* __restrict__ i_r,
    ushort* __restrict__ g_s, ushort* __restrict__ u_s,
    ushort* __restrict__ g_r, ushort* __restrict__ u_r,
    const ushort* __restrict__ swgT, const ushort* __restrict__ swuT,
    const ushort* __restrict__ wgT,  const ushort* __restrict__ wuT,
    const ushort* __restrict__ swdT, const ushort* __restrict__ wdT,
    float* __restrict__ out,
    const int* __restrict__ counts, const int* __restrict__ offs,
    const int* __restrict__ tlist,  const float* __restrict__ wlist)
{
  const int z = blockIdx.z;
  bool routed; int e = 0, K, N;
  const ushort* Bb; const ushort* Asrc = nullptr; ushort* O = nullptr;
  if constexpr (PHASE == 0){
    if (z < 2){ routed = false; K = 1024; N = 1024;
                Bb = z ? swuT : swgT; O = z ? u_s : g_s; Asrc = xb; }
    else { routed = true; e = (z - 2) & 15; bool up = (z >= 18);
           K = 1024; N = 512;
           Bb = (up ? wuT : wgT) + (size_t)e * MID * HID;
           O = up ? u_r : g_r; Asrc = xb; }
  } else {
    if (z == 0){ routed = false; K = 1024; N = 1024; Bb = swdT; Asrc = i_s; }
    else { routed = true; e = z - 1; K = 512; N = 1024;
           Bb = wdT + (size_t)e * HID * MID; Asrc = i_r; }
  }

  const int mbase = blockIdx.y * 128;
  const int nbase = blockIdx.x * 128;
  if (nbase >= N) return;
  int cnt = NTOKS, aoff = 0;
  if (routed){
    cnt = counts[e];
    if (mbase >= cnt) return;
    aoff = offs[e];
  }

  __shared__ __align__(16) ushort As[128 * 64];
  __shared__ __align__(16) ushort Bs[128 * 64];

  const int tid  = threadIdx.x;
  const int l    = tid & 63;
  const int w    = tid >> 6;
  const int wm = w >> 1, wn = w & 1;

  const int rl     = l >> 3;                 // 0..7 row-in-chunk
  const int srcOff = 8 * ((l & 7) ^ rl);     // inverse-swizzled source col (elems)

  const ushort* aP[4]; const ushort* bP[4];
  #pragma unroll
  for (int i = 0; i < 4; ++i){
    int r  = i * 32 + w * 8 + rl;            // LDS row this lane fills
    int ar = mbase + r;
    if constexpr (PHASE == 0){
      if (!routed) aP[i] = Asrc + (size_t)ar * 1024;
      else {
        int s = aoff + (ar < cnt ? ar : cnt - 1);
        aP[i] = Asrc + (size_t)tlist[s] * 1024;
      }
    } else {
      if (!routed) aP[i] = Asrc + (size_t)ar * 1024;
      else {
        int s = aoff + (ar < cnt ? ar : cnt - 1);
        aP[i] = Asrc + (size_t)s * 512;
      }
    }
    bP[i] = Bb + (size_t)(nbase + r) * K;
    aP[i] += srcOff;
    bP[i] += srcOff;
  }

  f32x4 acc[4][4];
  #pragma unroll
  for (int i = 0; i < 4; ++i)
    #pragma unroll
    for (int j = 0; j < 4; ++j)
      acc[i][j] = (f32x4){0.f, 0.f, 0.f, 0.f};

  const int fr  = l & 15;
  const int ko  = l >> 4;                    // 0..3
  const int swz = (fr & 7) << 4;             // frag-read XOR (bytes)
  const int nk  = K >> 6;

  for (int kt = 0; kt < nk; ++kt){
    const int ke = kt * 64;
    #pragma unroll
    for (int i = 0; i < 4; ++i){
      GLD16(aP[i] + ke, (ushort*)As + i * 2048 + w * 512);
      GLD16(bP[i] + ke, (ushort*)Bs + i * 2048 + w * 512);
    }
    __syncthreads();
    #pragma unroll
    for (int ks = 0; ks < 2; ++ks){
      const int co = ks * 64 + ko * 16;
      bf16x8 af[4], bf[4];
      #pragma unroll
      for (int mf = 0; mf < 4; ++mf)
        af[mf] = *reinterpret_cast<const bf16x8*>(
            (const char*)As + (wm*64 + mf*16 + fr) * 128 + (co ^ swz));
      #pragma unroll
      for (int nf = 0; nf < 4; ++nf)
        bf[nf] = *reinterpret_cast<const bf16x8*>(
            (const char*)Bs + (wn*64 + nf*16 + fr) * 128 + (co ^ swz));
      #pragma unroll
      for (int mf = 0; mf < 4; ++mf)
        #pragma unroll
        for (int nf = 0; nf < 4; ++nf)
          acc[mf][nf] = __builtin_amdgcn_mfma_f32_16x16x32_bf16(af[mf], bf[nf], acc[mf][nf], 0, 0, 0);
    }
    __syncthreads();
  }

  // epilogue: C/D map col = lane&15, row = (lane>>4)*4 + reg
  const int ccol = l & 15;
  const int crow = (l >> 4) * 4;
  #pragma unroll
  for (int mf = 0; mf < 4; ++mf){
    #pragma unroll
    for (int r_ = 0; r_ < 4; ++r_){
      const int rt = wm*64 + mf*16 + crow + r_;
      const int ar = mbase + rt;
      if (routed && ar >= cnt) continue;
      if constexpr (PHASE == 0){
        size_t row = routed ? (size_t)(aoff + ar) : (size_t)ar;
        #pragma unroll
        for (int nf = 0; nf < 4; ++nf){
          int ct = wn*64 + nf*16 + ccol;
          O[row * N + nbase + ct] = f2bf(acc[mf][nf][r_]);
        }
      } else {
        int tok; float wgt;
        if (!routed){ tok = ar; wgt = 1.f; }
        else { int s = aoff + ar; tok = tlist[s]; wgt = wlist[s]; }
        #pragma unroll
        for (int nf = 0; nf < 4; ++nf){
          int ct = wn*64 + nf*16 + ccol;
          atomicAdd(&out[(size_t)tok * 1024 + nbase + ct], wgt * acc[mf][nf][r_]);
        }
      }
    }
  }
}

// ---------------- silu-mul (in place into g buffers) ----------------
__global__ __launch_bounds__(256) void k_silu(ushort* __restrict__ g_s,
                                              const ushort* __restrict__ u_s,
                                              ushort* __restrict__ g_r,
                                              const ushort* __restrict__ u_r)
{
  int idx = blockIdx.x * 256 + threadIdx.x;   // 786432 total vec8
  ushort* G; const ushort* U; size_t p;
  if (idx < 262144){ G = g_s; U = u_s; p = (size_t)idx * 8; }
  else { G = g_r; U = u_r; p = (size_t)(idx - 262144) * 8; }
  u16x8 gv = *reinterpret_cast<const u16x8*>(G + p);
  u16x8 uv = *reinterpret_cast<const u16x8*>(U + p);
  u16x8 o;
  #pragma unroll
  for (int j = 0; j < 8; ++j){
    float g = bf2f(gv[j]), u = bf2f(uv[j]);
    float s = g / (1.f + expf(-g));
    o[j] = f2bf(s * u);
  }
  *reinterpret_cast<u16x8*>(G + p) = o;
}

// ---------------- launcher ----------------
extern "C" void kernel_launch(void* const* d_in, const int* in_sizes, int n_in,
                              void* d_out, int out_size, void* d_ws, size_t ws_size,
                              hipStream_t stream)
{
  const float* x   = (const float*)d_in[0];
  const float* gk  = (const float*)d_in[1];
  const float* gb  = (const float*)d_in[2];
  const float* wg  = (const float*)d_in[3];
  const float* wu  = (const float*)d_in[4];
  const float* wd  = (const float*)d_in[5];
  const float* swg = (const float*)d_in[6];
  const float* swu = (const float*)d_in[7];
  const float* swd = (const float*)d_in[8];
  float* out = (float*)d_out;
  char* ws = (char*)d_ws;

  const size_t MB = 1ull << 20;
  int*    counts = (int*)(ws + 0);
  int*    cursor = (int*)(ws + 64);
  int*    offs   = (int*)(ws + 128);
  int*    tidx   = (int*)(ws + 4096);
  float*  tw     = (float*)(ws + 36864);
  int*    tlist  = (int*)(ws + 69632);
  float*  wlist  = (float*)(ws + 102400);
  ushort* xb     = (ushort*)(ws + 1*MB);    // [2048][1024]
  ushort* swgT   = (ushort*)(ws + 5*MB);    // [1024][1024]
  ushort* swuT   = (ushort*)(ws + 7*MB);
  ushort* swdT   = (ushort*)(ws + 9*MB);
  ushort* wgT    = (ushort*)(ws + 11*MB);   // [16][512][1024]
  ushort* wuT    = (ushort*)(ws + 27*MB);
  ushort* wdT    = (ushort*)(ws + 43*MB);   // [16][1024][512]
  ushort* g_s    = (ushort*)(ws + 59*MB);   // [2048][1024]
  ushort* u_s    = (ushort*)(ws + 63*MB);
  ushort* g_r    = (ushort*)(ws + 67*MB);   // [8192][512]
  ushort* u_r    = (ushort*)(ws + 75*MB);

  hipMemsetAsync(counts, 0, 64, stream);
  k_gate<<<NTOKS, 64, 0, stream>>>(x, gk, gb, counts, tidx, tw);
  k_scan<<<1, 64, 0, stream>>>(counts, offs, cursor);
  k_place<<<NTOKS/256, 256, 0, stream>>>(tidx, tw, offs, cursor, tlist, wlist);

  // prep: bf16 conversions and weight transposes
  k_cvt<<<1024, 256, 0, stream>>>(x, xb, 262144);
  k_tr<<<dim3(16,16, 1), 256, 0, stream>>>(swg, swgT, 1024, 1024);
  k_tr<<<dim3(16,16, 1), 256, 0, stream>>>(swu, swuT, 1024, 1024);
  k_tr<<<dim3(16,16, 1), 256, 0, stream>>>(swd, swdT, 1024, 1024);
  k_tr<<<dim3( 8,16,16), 256, 0, stream>>>(wg,  wgT,  1024,  512);
  k_tr<<<dim3( 8,16,16), 256, 0, stream>>>(wu,  wuT,  1024,  512);
  k_tr<<<dim3(16, 8,16), 256, 0, stream>>>(wd,  wdT,   512, 1024);

  // gate+up mega GEMM (shared + routed in one launch)
  k_mm<0><<<dim3(8,16,34), 256, 0, stream>>>(xb, nullptr, nullptr,
      g_s, u_s, g_r, u_r, swgT, swuT, wgT, wuT, swdT, wdT, out,
      counts, offs, tlist, wlist);

  // silu(g)*u in place into g buffers
  k_silu<<<3072, 256, 0, stream>>>(g_s, u_s, g_r, u_r);

  // down mega GEMM accumulates into zeroed out
  hipMemsetAsync(out, 0, (size_t)NTOKS * HID * sizeof(float), stream);
  k_mm<1><<<dim3(8,16,17), 256, 0, stream>>>(xb, g_s, g_r,
      nullptr, nullptr, nullptr, nullptr, swgT, swuT, wgT, wuT, swdT, wdT, out,
      counts, offs, tlist, wlist);
}

// Round 3
// 211.039 us; speedup vs baseline: 2.7535x; 1.4627x over previous
//
#include <hip/hip_runtime.h>
#include <hip/hip_bf16.h>
#include <cstdint>

#define HID    1024
#define MID    512
#define NEXP   16
#define NTOKS  2048
#define TOPKE  4
#define RSCALE 2.5f
#define CSTR   16   // counter padding stride (ints) = 64B

typedef __attribute__((ext_vector_type(8))) short  bf16x8;
typedef __attribute__((ext_vector_type(8))) ushort u16x8;
typedef __attribute__((ext_vector_type(4))) float  f32x4;

__device__ __forceinline__ ushort f2bf(float f){
  unsigned u = __float_as_uint(f);
  u += 0x7fffu + ((u >> 16) & 1u);
  return (ushort)(u >> 16);
}
__device__ __forceinline__ float bf2f(ushort h){ return __uint_as_float(((unsigned)h) << 16); }

#define GLD16(g, l) __builtin_amdgcn_global_load_lds( \
    (const __attribute__((address_space(1))) unsigned int*)(g), \
    (__attribute__((address_space(3))) unsigned int*)(l), 16, 0, 0)

// ---------------- routing: logits + topk + aggregated counts ----------------
__global__ __launch_bounds__(256) void k_route(const float* __restrict__ x,
                                               const float* __restrict__ gk,
                                               const float* __restrict__ gb,
                                               int* __restrict__ counts,   // padded [16*CSTR]
                                               int* __restrict__ tidx,
                                               float* __restrict__ tw)
{
  __shared__ float sc[16][16];
  __shared__ int lcnt[NEXP];
  const int tid = threadIdx.x;
  const int tl  = tid >> 4;       // token-local 0..15
  const int e   = tid & 15;       // expert
  const int t   = blockIdx.x * 16 + tl;

  float acc = 0.f;
  const float* xr = x + (size_t)t * HID;
  for (int h = 0; h < HID; h += 4){
    f32x4 xv = *reinterpret_cast<const f32x4*>(xr + h);
    acc += xv[0] * gk[(h+0)*NEXP + e];
    acc += xv[1] * gk[(h+1)*NEXP + e];
    acc += xv[2] * gk[(h+2)*NEXP + e];
    acc += xv[3] * gk[(h+3)*NEXP + e];
  }
  sc[tl][e] = 1.f / (1.f + expf(-acc)) + gb[e];
  if (tid < NEXP) lcnt[tid] = 0;
  __syncthreads();

  if (tid < 16){
    const int tt = blockIdx.x * 16 + tid;
    float s4[NEXP];
    #pragma unroll
    for (int i = 0; i < NEXP; ++i) s4[i] = sc[tid][i];
    float gs[4];
    #pragma unroll
    for (int g = 0; g < 4; ++g){
      float m1 = -1e30f, m2 = -1e30f;
      #pragma unroll
      for (int j = 0; j < 4; ++j){
        float v = s4[g*4+j];
        if (v > m1){ m2 = m1; m1 = v; } else if (v > m2){ m2 = v; }
      }
      gs[g] = m1 + m2;
    }
    int g1 = 0;
    for (int g = 1; g < 4; ++g) if (gs[g] > gs[g1]) g1 = g;
    int g2 = -1;
    for (int g = 0; g < 4; ++g){
      if (g == g1) continue;
      if (g2 < 0 || gs[g] > gs[g2]) g2 = g;
    }
    float ms[NEXP];
    #pragma unroll
    for (int i = 0; i < NEXP; ++i){
      int g = i >> 2;
      ms[i] = (g == g1 || g == g2) ? s4[i] : 0.0f;
    }
    bool used[NEXP];
    #pragma unroll
    for (int i = 0; i < NEXP; ++i) used[i] = false;
    int sel[TOPKE]; float val[TOPKE]; float denom = 0.f;
    #pragma unroll
    for (int k = 0; k < TOPKE; ++k){
      int be = -1; float bv = -1e30f;
      for (int i = 0; i < NEXP; ++i){
        if (used[i]) continue;
        if (ms[i] > bv){ bv = ms[i]; be = i; }
      }
      used[be] = true; sel[k] = be; val[k] = bv; denom += bv;
    }
    float inv = RSCALE / (denom + 1e-20f);
    #pragma unroll
    for (int k = 0; k < TOPKE; ++k){
      tidx[tt*TOPKE + k] = sel[k];
      tw  [tt*TOPKE + k] = val[k] * inv;
      atomicAdd(&lcnt[sel[k]], 1);
    }
  }
  __syncthreads();
  if (tid < NEXP && lcnt[tid]) atomicAdd(&counts[tid * CSTR], lcnt[tid]);
}

__global__ void k_scan(const int* __restrict__ counts, int* __restrict__ offs,
                       int* __restrict__ cursor)
{
  if (threadIdx.x == 0){
    int s = 0;
    for (int e = 0; e < NEXP; ++e){ offs[e] = s; s += counts[e * CSTR]; }
    offs[NEXP] = s;
  }
  if (threadIdx.x < NEXP) cursor[threadIdx.x * CSTR] = 0;
}

__global__ __launch_bounds__(256) void k_place(const int* __restrict__ tidx,
                                               const float* __restrict__ tw,
                                               const int* __restrict__ offs,
                                               int* __restrict__ cursor,
                                               int* __restrict__ tlist,
                                               float* __restrict__ wlist)
{
  __shared__ int lcnt[NEXP];
  __shared__ int lbase[NEXP];
  const int tid = threadIdx.x;
  const int t = blockIdx.x * 256 + tid;
  if (tid < NEXP) lcnt[tid] = 0;
  __syncthreads();
  int sel[TOPKE]; float w4[TOPKE]; int ls[TOPKE];
  #pragma unroll
  for (int k = 0; k < TOPKE; ++k){
    sel[k] = tidx[t*TOPKE + k];
    w4[k]  = tw[t*TOPKE + k];
    ls[k]  = atomicAdd(&lcnt[sel[k]], 1);
  }
  __syncthreads();
  if (tid < NEXP) lbase[tid] = atomicAdd(&cursor[tid * CSTR], lcnt[tid]);
  __syncthreads();
  #pragma unroll
  for (int k = 0; k < TOPKE; ++k){
    int p = offs[sel[k]] + lbase[sel[k]] + ls[k];
    tlist[p] = t;
    wlist[p] = w4[k];
  }
}

// ---------------- prep: fp32 -> bf16 convert ----------------
__global__ __launch_bounds__(256) void k_cvt(const float* __restrict__ in,
                                             ushort* __restrict__ out, int n8)
{
  int i = blockIdx.x * 256 + threadIdx.x;
  if (i >= n8) return;
  f32x4 a = *reinterpret_cast<const f32x4*>(in + (size_t)i*8);
  f32x4 b = *reinterpret_cast<const f32x4*>(in + (size_t)i*8 + 4);
  u16x8 o;
  o[0]=f2bf(a[0]); o[1]=f2bf(a[1]); o[2]=f2bf(a[2]); o[3]=f2bf(a[3]);
  o[4]=f2bf(b[0]); o[5]=f2bf(b[1]); o[6]=f2bf(b[2]); o[7]=f2bf(b[3]);
  *reinterpret_cast<u16x8*>(out + (size_t)i*8) = o;
}

// ---------------- prep: fp32 [K][N] -> bf16 [N][K] transpose ----------------
__global__ __launch_bounds__(256) void k_tr(const float* __restrict__ in,
                                            ushort* __restrict__ out, int K, int N)
{
  const int e = blockIdx.z;
  in  += (size_t)e * K * N;
  out += (size_t)e * K * N;
  const int kb = blockIdx.y * 64, nb = blockIdx.x * 64;
  __shared__ ushort T[64 * 68];
  const int t = threadIdx.x;
  const int r = t >> 4, c4 = (t & 15) * 4;
  #pragma unroll
  for (int i = 0; i < 4; ++i){
    f32x4 v = *reinterpret_cast<const f32x4*>(in + (size_t)(kb + r + i*16) * N + nb + c4);
    #pragma unroll
    for (int j = 0; j < 4; ++j)
      T[(c4 + j) * 68 + r + i*16] = f2bf(v[j]);
  }
  __syncthreads();
  #pragma unroll
  for (int i = 0; i < 4; ++i){
    int n = r + i*16;
    ushort4 o = *reinterpret_cast<const ushort4*>(&T[n * 68 + c4]);
    *reinterpret_cast<ushort4*>(out + (size_t)(nb + n) * K + kb + c4) = o;
  }
}

// ---------------- mega GEMM (m97 structure) ----------------
template<int PHASE>
__global__ __launch_bounds__(256) void k_mm(
    const ushort* __restrict__ xb,
    const ushort* __restrict__ i_s,  const ushort* __restrict__ i_r,
    ushort* __restrict__ g_s, ushort* __restrict__ u_s,
    ushort* __restrict__ g_r, ushort* __restrict__ u_r,
    const ushort* __restrict__ swgT, const ushort* __restrict__ swuT,
    const ushort* __restrict__ wgT,  const ushort* __restrict__ wuT,
    const ushort* __restrict__ swdT, const ushort* __restrict__ wdT,
    float* __restrict__ out,
    const int* __restrict__ counts, const int* __restrict__ offs,
    const int* __restrict__ tlist,  const float* __restrict__ wlist)
{
  const int z = blockIdx.z;
  bool routed; int e = 0, K, N;
  const ushort* Bb; const ushort* Asrc = nullptr; ushort* O = nullptr;
  if constexpr (PHASE == 0){
    if (z < 2){ routed = false; K = 1024; N = 1024;
                Bb = z ? swuT : swgT; O = z ? u_s : g_s; Asrc = xb; }
    else { routed = true; e = (z - 2) & 15; bool up = (z >= 18);
           K = 1024; N = 512;
           Bb = (up ? wuT : wgT) + (size_t)e * MID * HID;
           O = up ? u_r : g_r; Asrc = xb; }
  } else {
    if (z == 0){ routed = false; K = 1024; N = 1024; Bb = swdT; Asrc = i_s; }
    else { routed = true; e = z - 1; K = 512; N = 1024;
           Bb = wdT + (size_t)e * HID * MID; Asrc = i_r; }
  }

  const int mbase = blockIdx.y * 128;
  const int nbase = blockIdx.x * 128;
  if (nbase >= N) return;
  int cnt = NTOKS, aoff = 0;
  if (routed){
    cnt = counts[e * CSTR];
    if (mbase >= cnt) return;
    aoff = offs[e];
  }

  __shared__ __align__(16) ushort As[128 * 64];
  __shared__ __align__(16) ushort Bs[128 * 64];

  const int tid  = threadIdx.x;
  const int l    = tid & 63;
  const int w    = tid >> 6;
  const int wm = w >> 1, wn = w & 1;

  const int rl     = l >> 3;
  const int srcOff = 8 * ((l & 7) ^ rl);

  const ushort* aP[4]; const ushort* bP[4];
  #pragma unroll
  for (int i = 0; i < 4; ++i){
    int r  = i * 32 + w * 8 + rl;
    int ar = mbase + r;
    if constexpr (PHASE == 0){
      if (!routed) aP[i] = Asrc + (size_t)ar * 1024;
      else {
        int s = aoff + (ar < cnt ? ar : cnt - 1);
        aP[i] = Asrc + (size_t)tlist[s] * 1024;
      }
    } else {
      if (!routed) aP[i] = Asrc + (size_t)ar * 1024;
      else {
        int s = aoff + (ar < cnt ? ar : cnt - 1);
        aP[i] = Asrc + (size_t)s * 512;
      }
    }
    bP[i] = Bb + (size_t)(nbase + r) * K;
    aP[i] += srcOff;
    bP[i] += srcOff;
  }

  f32x4 acc[4][4];
  #pragma unroll
  for (int i = 0; i < 4; ++i)
    #pragma unroll
    for (int j = 0; j < 4; ++j)
      acc[i][j] = (f32x4){0.f, 0.f, 0.f, 0.f};

  const int fr  = l & 15;
  const int ko  = l >> 4;
  const int swz = (fr & 7) << 4;
  const int nk  = K >> 6;

  for (int kt = 0; kt < nk; ++kt){
    const int ke = kt * 64;
    #pragma unroll
    for (int i = 0; i < 4; ++i){
      GLD16(aP[i] + ke, (ushort*)As + i * 2048 + w * 512);
      GLD16(bP[i] + ke, (ushort*)Bs + i * 2048 + w * 512);
    }
    __syncthreads();
    #pragma unroll
    for (int ks = 0; ks < 2; ++ks){
      const int co = ks * 64 + ko * 16;
      bf16x8 af[4], bf[4];
      #pragma unroll
      for (int mf = 0; mf < 4; ++mf)
        af[mf] = *reinterpret_cast<const bf16x8*>(
            (const char*)As + (wm*64 + mf*16 + fr) * 128 + (co ^ swz));
      #pragma unroll
      for (int nf = 0; nf < 4; ++nf)
        bf[nf] = *reinterpret_cast<const bf16x8*>(
            (const char*)Bs + (wn*64 + nf*16 + fr) * 128 + (co ^ swz));
      #pragma unroll
      for (int mf = 0; mf < 4; ++mf)
        #pragma unroll
        for (int nf = 0; nf < 4; ++nf)
          acc[mf][nf] = __builtin_amdgcn_mfma_f32_16x16x32_bf16(af[mf], bf[nf], acc[mf][nf], 0, 0, 0);
    }
    __syncthreads();
  }

  const int ccol = l & 15;
  const int crow = (l >> 4) * 4;
  #pragma unroll
  for (int mf = 0; mf < 4; ++mf){
    #pragma unroll
    for (int r_ = 0; r_ < 4; ++r_){
      const int rt = wm*64 + mf*16 + crow + r_;
      const int ar = mbase + rt;
      if (routed && ar >= cnt) continue;
      if constexpr (PHASE == 0){
        size_t row = routed ? (size_t)(aoff + ar) : (size_t)ar;
        #pragma unroll
        for (int nf = 0; nf < 4; ++nf){
          int ct = wn*64 + nf*16 + ccol;
          O[row * N + nbase + ct] = f2bf(acc[mf][nf][r_]);
        }
      } else {
        int tok; float wgt;
        if (!routed){ tok = ar; wgt = 1.f; }
        else { int s = aoff + ar; tok = tlist[s]; wgt = wlist[s]; }
        #pragma unroll
        for (int nf = 0; nf < 4; ++nf){
          int ct = wn*64 + nf*16 + ccol;
          atomicAdd(&out[(size_t)tok * 1024 + nbase + ct], wgt * acc[mf][nf][r_]);
        }
      }
    }
  }
}

// ---------------- silu-mul (in place into g buffers) ----------------
__global__ __launch_bounds__(256) void k_silu(ushort* __restrict__ g_s,
                                              const ushort* __restrict__ u_s,
                                              ushort* __restrict__ g_r,
                                              const ushort* __restrict__ u_r)
{
  int idx = blockIdx.x * 256 + threadIdx.x;
  ushort* G; const ushort* U; size_t p;
  if (idx < 262144){ G = g_s; U = u_s; p = (size_t)idx * 8; }
  else { G = g_r; U = u_r; p = (size_t)(idx - 262144) * 8; }
  u16x8 gv = *reinterpret_cast<const u16x8*>(G + p);
  u16x8 uv = *reinterpret_cast<const u16x8*>(U + p);
  u16x8 o;
  #pragma unroll
  for (int j = 0; j < 8; ++j){
    float g = bf2f(gv[j]), u = bf2f(uv[j]);
    float s = g / (1.f + expf(-g));
    o[j] = f2bf(s * u);
  }
  *reinterpret_cast<u16x8*>(G + p) = o;
}

// ---------------- launcher ----------------
extern "C" void kernel_launch(void* const* d_in, const int* in_sizes, int n_in,
                              void* d_out, int out_size, void* d_ws, size_t ws_size,
                              hipStream_t stream)
{
  const float* x   = (const float*)d_in[0];
  const float* gk  = (const float*)d_in[1];
  const float* gb  = (const float*)d_in[2];
  const float* wg  = (const float*)d_in[3];
  const float* wu  = (const float*)d_in[4];
  const float* wd  = (const float*)d_in[5];
  const float* swg = (const float*)d_in[6];
  const float* swu = (const float*)d_in[7];
  const float* swd = (const float*)d_in[8];
  float* out = (float*)d_out;
  char* ws = (char*)d_ws;

  const size_t MB = 1ull << 20;
  int*    counts = (int*)(ws + 0);        // padded 16*CSTR ints = 1KB
  int*    cursor = (int*)(ws + 2048);     // padded
  int*    offs   = (int*)(ws + 4096);
  int*    tidx   = (int*)(ws + 8192);     // [2048][4]
  float*  tw     = (float*)(ws + 49152);
  int*    tlist  = (int*)(ws + 90112);
  float*  wlist  = (float*)(ws + 131072);
  ushort* xb     = (ushort*)(ws + 1*MB);
  ushort* swgT   = (ushort*)(ws + 5*MB);
  ushort* swuT   = (ushort*)(ws + 7*MB);
  ushort* swdT   = (ushort*)(ws + 9*MB);
  ushort* wgT    = (ushort*)(ws + 11*MB);
  ushort* wuT    = (ushort*)(ws + 27*MB);
  ushort* wdT    = (ushort*)(ws + 43*MB);
  ushort* g_s    = (ushort*)(ws + 59*MB);
  ushort* u_s    = (ushort*)(ws + 63*MB);
  ushort* g_r    = (ushort*)(ws + 67*MB);
  ushort* u_r    = (ushort*)(ws + 75*MB);

  hipMemsetAsync(counts, 0, 16 * CSTR * sizeof(int), stream);
  k_route<<<128, 256, 0, stream>>>(x, gk, gb, counts, tidx, tw);
  k_scan<<<1, 64, 0, stream>>>(counts, offs, cursor);
  k_place<<<NTOKS/256, 256, 0, stream>>>(tidx, tw, offs, cursor, tlist, wlist);

  k_cvt<<<1024, 256, 0, stream>>>(x, xb, 262144);
  k_tr<<<dim3(16,16, 1), 256, 0, stream>>>(swg, swgT, 1024, 1024);
  k_tr<<<dim3(16,16, 1), 256, 0, stream>>>(swu, swuT, 1024, 1024);
  k_tr<<<dim3(16,16, 1), 256, 0, stream>>>(swd, swdT, 1024, 1024);
  k_tr<<<dim3( 8,16,16), 256, 0, stream>>>(wg,  wgT,  1024,  512);
  k_tr<<<dim3( 8,16,16), 256, 0, stream>>>(wu,  wuT,  1024,  512);
  k_tr<<<dim3(16, 8,16), 256, 0, stream>>>(wd,  wdT,   512, 1024);

  k_mm<0><<<dim3(8,16,34), 256, 0, stream>>>(xb, nullptr, nullptr,
      g_s, u_s, g_r, u_r, swgT, swuT, wgT, wuT, swdT, wdT, out,
      counts, offs, tlist, wlist);

  k_silu<<<3072, 256, 0, stream>>>(g_s, u_s, g_r, u_r);

  hipMemsetAsync(out, 0, (size_t)NTOKS * HID * sizeof(float), stream);
  k_mm<1><<<dim3(8,16,17), 256, 0, stream>>>(xb, g_s, g_r,
      nullptr, nullptr, nullptr, nullptr, swgT, swuT, wgT, wuT, swdT, wdT, out,
      counts, offs, tlist, wlist);
}

// Round 4
// 182.730 us; speedup vs baseline: 3.1800x; 1.1549x over previous
//
#include <hip/hip_runtime.h>
#include <hip/hip_bf16.h>
#include <cstdint>

#define HID    1024
#define MID    512
#define NEXP   16
#define NTOKS  2048
#define TOPKE  4
#define RSCALE 2.5f
#define CSTR   16   // counter padding stride (ints) = 64B

typedef __attribute__((ext_vector_type(8))) short  bf16x8;
typedef __attribute__((ext_vector_type(8))) ushort u16x8;
typedef __attribute__((ext_vector_type(4))) float  f32x4;

__device__ __forceinline__ ushort f2bf(float f){
  unsigned u = __float_as_uint(f);
  u += 0x7fffu + ((u >> 16) & 1u);
  return (ushort)(u >> 16);
}
__device__ __forceinline__ float bf2f(ushort h){ return __uint_as_float(((unsigned)h) << 16); }

#define GLD16(g, l) __builtin_amdgcn_global_load_lds( \
    (const __attribute__((address_space(1))) unsigned int*)(g), \
    (__attribute__((address_space(3))) unsigned int*)(l), 16, 0, 0)

// ---------------- routing ----------------
__global__ __launch_bounds__(256) void k_route(const float* __restrict__ x,
                                               const float* __restrict__ gk,
                                               const float* __restrict__ gb,
                                               int* __restrict__ counts,
                                               int* __restrict__ tidx,
                                               float* __restrict__ tw)
{
  __shared__ float sc[16][16];
  __shared__ int lcnt[NEXP];
  const int tid = threadIdx.x;
  const int tl  = tid >> 4;
  const int e   = tid & 15;
  const int t   = blockIdx.x * 16 + tl;

  float acc = 0.f;
  const float* xr = x + (size_t)t * HID;
  for (int h = 0; h < HID; h += 4){
    f32x4 xv = *reinterpret_cast<const f32x4*>(xr + h);
    acc += xv[0] * gk[(h+0)*NEXP + e];
    acc += xv[1] * gk[(h+1)*NEXP + e];
    acc += xv[2] * gk[(h+2)*NEXP + e];
    acc += xv[3] * gk[(h+3)*NEXP + e];
  }
  sc[tl][e] = 1.f / (1.f + expf(-acc)) + gb[e];
  if (tid < NEXP) lcnt[tid] = 0;
  __syncthreads();

  if (tid < 16){
    const int tt = blockIdx.x * 16 + tid;
    float s4[NEXP];
    #pragma unroll
    for (int i = 0; i < NEXP; ++i) s4[i] = sc[tid][i];
    float gs[4];
    #pragma unroll
    for (int g = 0; g < 4; ++g){
      float m1 = -1e30f, m2 = -1e30f;
      #pragma unroll
      for (int j = 0; j < 4; ++j){
        float v = s4[g*4+j];
        if (v > m1){ m2 = m1; m1 = v; } else if (v > m2){ m2 = v; }
      }
      gs[g] = m1 + m2;
    }
    int g1 = 0;
    for (int g = 1; g < 4; ++g) if (gs[g] > gs[g1]) g1 = g;
    int g2 = -1;
    for (int g = 0; g < 4; ++g){
      if (g == g1) continue;
      if (g2 < 0 || gs[g] > gs[g2]) g2 = g;
    }
    float ms[NEXP];
    #pragma unroll
    for (int i = 0; i < NEXP; ++i){
      int g = i >> 2;
      ms[i] = (g == g1 || g == g2) ? s4[i] : 0.0f;
    }
    bool used[NEXP];
    #pragma unroll
    for (int i = 0; i < NEXP; ++i) used[i] = false;
    int sel[TOPKE]; float val[TOPKE]; float denom = 0.f;
    #pragma unroll
    for (int k = 0; k < TOPKE; ++k){
      int be = -1; float bv = -1e30f;
      for (int i = 0; i < NEXP; ++i){
        if (used[i]) continue;
        if (ms[i] > bv){ bv = ms[i]; be = i; }
      }
      used[be] = true; sel[k] = be; val[k] = bv; denom += bv;
    }
    float inv = RSCALE / (denom + 1e-20f);
    #pragma unroll
    for (int k = 0; k < TOPKE; ++k){
      tidx[tt*TOPKE + k] = sel[k];
      tw  [tt*TOPKE + k] = val[k] * inv;
      atomicAdd(&lcnt[sel[k]], 1);
    }
  }
  __syncthreads();
  if (tid < NEXP && lcnt[tid]) atomicAdd(&counts[tid * CSTR], lcnt[tid]);
}

__global__ void k_scan(const int* __restrict__ counts, int* __restrict__ offs,
                       int* __restrict__ cursor)
{
  if (threadIdx.x == 0){
    int s = 0;
    for (int e = 0; e < NEXP; ++e){ offs[e] = s; s += counts[e * CSTR]; }
    offs[NEXP] = s;
  }
  if (threadIdx.x < NEXP) cursor[threadIdx.x * CSTR] = 0;
}

__global__ __launch_bounds__(256) void k_place(const int* __restrict__ tidx,
                                               const float* __restrict__ tw,
                                               const int* __restrict__ offs,
                                               int* __restrict__ cursor,
                                               int* __restrict__ tlist,
                                               float* __restrict__ wlist,
                                               int* __restrict__ pos)
{
  __shared__ int lcnt[NEXP];
  __shared__ int lbase[NEXP];
  const int tid = threadIdx.x;
  const int t = blockIdx.x * 256 + tid;
  if (tid < NEXP) lcnt[tid] = 0;
  __syncthreads();
  int sel[TOPKE]; float w4[TOPKE]; int ls[TOPKE];
  #pragma unroll
  for (int k = 0; k < TOPKE; ++k){
    sel[k] = tidx[t*TOPKE + k];
    w4[k]  = tw[t*TOPKE + k];
    ls[k]  = atomicAdd(&lcnt[sel[k]], 1);
  }
  __syncthreads();
  if (tid < NEXP) lbase[tid] = atomicAdd(&cursor[tid * CSTR], lcnt[tid]);
  __syncthreads();
  #pragma unroll
  for (int k = 0; k < TOPKE; ++k){
    int p = offs[sel[k]] + lbase[sel[k]] + ls[k];
    tlist[p] = t;
    wlist[p] = w4[k];
    pos[t*TOPKE + k] = p;
  }
}

// ---------------- prep ----------------
__global__ __launch_bounds__(256) void k_cvt(const float* __restrict__ in,
                                             ushort* __restrict__ out, int n8)
{
  int i = blockIdx.x * 256 + threadIdx.x;
  if (i >= n8) return;
  f32x4 a = *reinterpret_cast<const f32x4*>(in + (size_t)i*8);
  f32x4 b = *reinterpret_cast<const f32x4*>(in + (size_t)i*8 + 4);
  u16x8 o;
  o[0]=f2bf(a[0]); o[1]=f2bf(a[1]); o[2]=f2bf(a[2]); o[3]=f2bf(a[3]);
  o[4]=f2bf(b[0]); o[5]=f2bf(b[1]); o[6]=f2bf(b[2]); o[7]=f2bf(b[3]);
  *reinterpret_cast<u16x8*>(out + (size_t)i*8) = o;
}

__global__ __launch_bounds__(256) void k_tr(const float* __restrict__ in,
                                            ushort* __restrict__ out, int K, int N)
{
  const int e = blockIdx.z;
  in  += (size_t)e * K * N;
  out += (size_t)e * K * N;
  const int kb = blockIdx.y * 64, nb = blockIdx.x * 64;
  __shared__ ushort T[64 * 68];
  const int t = threadIdx.x;
  const int r = t >> 4, c4 = (t & 15) * 4;
  #pragma unroll
  for (int i = 0; i < 4; ++i){
    f32x4 v = *reinterpret_cast<const f32x4*>(in + (size_t)(kb + r + i*16) * N + nb + c4);
    #pragma unroll
    for (int j = 0; j < 4; ++j)
      T[(c4 + j) * 68 + r + i*16] = f2bf(v[j]);
  }
  __syncthreads();
  #pragma unroll
  for (int i = 0; i < 4; ++i){
    int n = r + i*16;
    ushort4 o = *reinterpret_cast<const ushort4*>(&T[n * 68 + c4]);
    *reinterpret_cast<ushort4*>(out + (size_t)(nb + n) * K + kb + c4) = o;
  }
}

// ---------------- phase 0: fused gate+up+silu ----------------
// 512 thr (8 waves). Tile 128 rows x 128 cols of BOTH gate and up.
// z=0: shared (N=1024, x<8), z=1..16: expert e=z-1 (N=512, x<4).
// K=1024 always. LDS: A 16KB | Bg 16KB | Bu 16KB.
__global__ __launch_bounds__(512) void k_mm0(
    const ushort* __restrict__ xb,
    ushort* __restrict__ i_s, ushort* __restrict__ i_r,
    const ushort* __restrict__ swgT, const ushort* __restrict__ swuT,
    const ushort* __restrict__ wgT,  const ushort* __restrict__ wuT,
    const int* __restrict__ counts, const int* __restrict__ offs,
    const int* __restrict__ tlist)
{
  const int z = blockIdx.z;
  const bool routed = (z > 0);
  const int e = z - 1;
  const int N = routed ? 512 : 1024;
  const int nbase = blockIdx.x * 128;
  if (nbase >= N) return;
  const int mbase = blockIdx.y * 128;
  int cnt = NTOKS, aoff = 0;
  if (routed){
    cnt = counts[e * CSTR];
    if (mbase >= cnt) return;
    aoff = offs[e];
  }
  const ushort* Bg = routed ? (wgT + (size_t)e * MID * HID) : swgT;
  const ushort* Bu = routed ? (wuT + (size_t)e * MID * HID) : swuT;
  ushort* O = routed ? i_r : i_s;

  __shared__ __align__(16) ushort Sh[3 * 128 * 64];   // 48KB

  const int tid = threadIdx.x;
  const int l   = tid & 63;
  const int w   = tid >> 6;          // 0..7
  const int wm  = w >> 2;            // 0..1 rows
  const int wn  = w & 3;             // 0..3 cols (32-wide, both halves)

  const int rl     = l >> 3;
  const int srcOff = 8 * ((l & 7) ^ rl);

  const ushort* srcP[6];
  #pragma unroll
  for (int j = 0; j < 6; ++j){
    int g = w * 6 + j;
    int b = g >> 4;                 // 0=A 1=Bg 2=Bu
    int r = (g & 15) * 8 + rl;
    const ushort* p;
    if (b == 0){
      int ar = mbase + r;
      if (routed){
        int s = aoff + (ar < cnt ? ar : cnt - 1);
        p = xb + (size_t)tlist[s] * HID;
      } else p = xb + (size_t)ar * HID;
    } else if (b == 1){
      p = Bg + (size_t)(nbase + r) * HID;
    } else {
      p = Bu + (size_t)(nbase + r) * HID;
    }
    srcP[j] = p + srcOff;
  }

  f32x4 accg[4][2], accu[4][2];
  #pragma unroll
  for (int i = 0; i < 4; ++i)
    #pragma unroll
    for (int j = 0; j < 2; ++j){
      accg[i][j] = (f32x4){0.f,0.f,0.f,0.f};
      accu[i][j] = (f32x4){0.f,0.f,0.f,0.f};
    }

  const int fr  = l & 15;
  const int ko  = l >> 4;
  const int swz = (fr & 7) << 4;

  for (int kt = 0; kt < 16; ++kt){
    const int ke = kt * 64;
    #pragma unroll
    for (int j = 0; j < 6; ++j)
      GLD16(srcP[j] + ke, (ushort*)Sh + (w*6 + j) * 512);
    __syncthreads();
    #pragma unroll
    for (int ks = 0; ks < 2; ++ks){
      const int co = ks * 64 + ko * 16;
      bf16x8 af[4], bg[2], bu[2];
      #pragma unroll
      for (int mf = 0; mf < 4; ++mf)
        af[mf] = *reinterpret_cast<const bf16x8*>(
            (const char*)Sh + (wm*64 + mf*16 + fr) * 128 + (co ^ swz));
      #pragma unroll
      for (int nf = 0; nf < 2; ++nf){
        int cc = wn*32 + nf*16 + fr;
        bg[nf] = *reinterpret_cast<const bf16x8*>(
            (const char*)Sh + 16384 + cc * 128 + (co ^ swz));
        bu[nf] = *reinterpret_cast<const bf16x8*>(
            (const char*)Sh + 32768 + cc * 128 + (co ^ swz));
      }
      #pragma unroll
      for (int mf = 0; mf < 4; ++mf)
        #pragma unroll
        for (int nf = 0; nf < 2; ++nf){
          accg[mf][nf] = __builtin_amdgcn_mfma_f32_16x16x32_bf16(af[mf], bg[nf], accg[mf][nf], 0, 0, 0);
          accu[mf][nf] = __builtin_amdgcn_mfma_f32_16x16x32_bf16(af[mf], bu[nf], accu[mf][nf], 0, 0, 0);
        }
    }
    __syncthreads();
  }

  const int ccol = l & 15;
  const int crow = (l >> 4) * 4;
  #pragma unroll
  for (int mf = 0; mf < 4; ++mf){
    #pragma unroll
    for (int r_ = 0; r_ < 4; ++r_){
      const int arel = wm*64 + mf*16 + crow + r_ + mbase;
      if (routed && arel >= cnt) continue;
      size_t row = routed ? (size_t)(aoff + arel) : (size_t)arel;
      #pragma unroll
      for (int nf = 0; nf < 2; ++nf){
        int col = nbase + wn*32 + nf*16 + ccol;
        float g = accg[mf][nf][r_];
        float u = accu[mf][nf][r_];
        float s = g / (1.f + expf(-g));
        O[row * N + col] = f2bf(s * u);
      }
    }
  }
}

// ---------------- phase 1: down-proj, 2 M-tiles/block, plain stores ----------------
// 512 thr. Output 256 rows x 128 cols. z=0: shared (A=i_s,K=1024 -> y_s),
// z=1..16: routed (A=i_r,K=512 -> y_r, weight applied). LDS: A 32KB | B 16KB.
__global__ __launch_bounds__(512) void k_mm1(
    const ushort* __restrict__ i_s, const ushort* __restrict__ i_r,
    const ushort* __restrict__ swdT, const ushort* __restrict__ wdT,
    ushort* __restrict__ y_s, ushort* __restrict__ y_r,
    const int* __restrict__ counts, const int* __restrict__ offs,
    const float* __restrict__ wlist)
{
  const int z = blockIdx.z;
  const bool routed = (z > 0);
  const int e = z - 1;
  const int Kd = routed ? MID : HID;
  const int mbase = blockIdx.y * 256;
  const int nbase = blockIdx.x * 128;
  int cnt = NTOKS, aoff = 0;
  if (routed){
    cnt = counts[e * CSTR];
    if (mbase >= cnt) return;
    aoff = offs[e];
  }
  const ushort* A = routed ? i_r : i_s;
  const ushort* B = routed ? (wdT + (size_t)e * HID * MID) : swdT;

  __shared__ __align__(16) ushort Sh[3 * 128 * 64];   // 48KB: A 32KB | B 16KB

  const int tid = threadIdx.x;
  const int l   = tid & 63;
  const int w   = tid >> 6;
  const int rg  = w >> 1;            // 0..3: rows rg*64
  const int cg  = w & 1;             // 0..1: cols cg*64

  const int rl     = l >> 3;
  const int srcOff = 8 * ((l & 7) ^ rl);

  const ushort* srcP[6];
  #pragma unroll
  for (int j = 0; j < 6; ++j){
    int g = w * 6 + j;
    const ushort* p;
    if (g < 32){
      int r = g * 8 + rl;            // A rows 0..255
      int ar = mbase + r;
      if (routed){
        int s = aoff + (ar < cnt ? ar : cnt - 1);
        p = A + (size_t)s * Kd;
      } else p = A + (size_t)ar * Kd;
    } else {
      int r = (g - 32) * 8 + rl;     // B rows 0..127
      p = B + (size_t)(nbase + r) * Kd;
    }
    srcP[j] = p + srcOff;
  }

  f32x4 acc[4][4];
  #pragma unroll
  for (int i = 0; i < 4; ++i)
    #pragma unroll
    for (int j = 0; j < 4; ++j)
      acc[i][j] = (f32x4){0.f,0.f,0.f,0.f};

  const int fr  = l & 15;
  const int ko  = l >> 4;
  const int swz = (fr & 7) << 4;
  const int nk  = Kd >> 6;

  for (int kt = 0; kt < nk; ++kt){
    const int ke = kt * 64;
    #pragma unroll
    for (int j = 0; j < 6; ++j)
      GLD16(srcP[j] + ke, (ushort*)Sh + (w*6 + j) * 512);
    __syncthreads();
    #pragma unroll
    for (int ks = 0; ks < 2; ++ks){
      const int co = ks * 64 + ko * 16;
      bf16x8 af[4], bf[4];
      #pragma unroll
      for (int mf = 0; mf < 4; ++mf)
        af[mf] = *reinterpret_cast<const bf16x8*>(
            (const char*)Sh + (rg*64 + mf*16 + fr) * 128 + (co ^ swz));
      #pragma unroll
      for (int nf = 0; nf < 4; ++nf)
        bf[nf] = *reinterpret_cast<const bf16x8*>(
            (const char*)Sh + 32768 + (cg*64 + nf*16 + fr) * 128 + (co ^ swz));
      #pragma unroll
      for (int mf = 0; mf < 4; ++mf)
        #pragma unroll
        for (int nf = 0; nf < 4; ++nf)
          acc[mf][nf] = __builtin_amdgcn_mfma_f32_16x16x32_bf16(af[mf], bf[nf], acc[mf][nf], 0, 0, 0);
    }
    __syncthreads();
  }

  const int ccol = l & 15;
  const int crow = (l >> 4) * 4;
  #pragma unroll
  for (int mf = 0; mf < 4; ++mf){
    #pragma unroll
    for (int r_ = 0; r_ < 4; ++r_){
      const int arel = rg*64 + mf*16 + crow + r_ + mbase;
      if (routed && arel >= cnt) continue;
      if (!routed){
        #pragma unroll
        for (int nf = 0; nf < 4; ++nf){
          int col = nbase + cg*64 + nf*16 + ccol;
          y_s[(size_t)arel * HID + col] = f2bf(acc[mf][nf][r_]);
        }
      } else {
        int s = aoff + arel;
        float wgt = wlist[s];
        #pragma unroll
        for (int nf = 0; nf < 4; ++nf){
          int col = nbase + cg*64 + nf*16 + ccol;
          y_r[(size_t)s * HID + col] = f2bf(wgt * acc[mf][nf][r_]);
        }
      }
    }
  }
}

// ---------------- combine: out = y_s + sum_k y_r[pos] ----------------
__global__ __launch_bounds__(256) void k_comb(const ushort* __restrict__ y_s,
                                              const ushort* __restrict__ y_r,
                                              const int* __restrict__ pos,
                                              float* __restrict__ out)
{
  const int t  = blockIdx.x * 2 + (threadIdx.x >> 7);
  const int c8 = (threadIdx.x & 127) * 8;
  const int* pp = pos + t * TOPKE;
  u16x8 vs = *reinterpret_cast<const u16x8*>(y_s + (size_t)t * HID + c8);
  float s[8];
  #pragma unroll
  for (int j = 0; j < 8; ++j) s[j] = bf2f(vs[j]);
  #pragma unroll
  for (int k = 0; k < TOPKE; ++k){
    int p = pp[k];
    u16x8 vr = *reinterpret_cast<const u16x8*>(y_r + (size_t)p * HID + c8);
    #pragma unroll
    for (int j = 0; j < 8; ++j) s[j] += bf2f(vr[j]);
  }
  f32x4 o0 = (f32x4){s[0],s[1],s[2],s[3]};
  f32x4 o1 = (f32x4){s[4],s[5],s[6],s[7]};
  *reinterpret_cast<f32x4*>(out + (size_t)t * HID + c8)     = o0;
  *reinterpret_cast<f32x4*>(out + (size_t)t * HID + c8 + 4) = o1;
}

// ---------------- launcher ----------------
extern "C" void kernel_launch(void* const* d_in, const int* in_sizes, int n_in,
                              void* d_out, int out_size, void* d_ws, size_t ws_size,
                              hipStream_t stream)
{
  const float* x   = (const float*)d_in[0];
  const float* gk  = (const float*)d_in[1];
  const float* gb  = (const float*)d_in[2];
  const float* wg  = (const float*)d_in[3];
  const float* wu  = (const float*)d_in[4];
  const float* wd  = (const float*)d_in[5];
  const float* swg = (const float*)d_in[6];
  const float* swu = (const float*)d_in[7];
  const float* swd = (const float*)d_in[8];
  float* out = (float*)d_out;
  char* ws = (char*)d_ws;

  const size_t MB = 1ull << 20;
  int*    counts = (int*)(ws + 0);
  int*    cursor = (int*)(ws + 2048);
  int*    offs   = (int*)(ws + 4096);
  int*    tidx   = (int*)(ws + 8192);
  float*  tw     = (float*)(ws + 49152);
  int*    tlist  = (int*)(ws + 90112);
  float*  wlist  = (float*)(ws + 131072);
  int*    pos    = (int*)(ws + 163840);
  ushort* xb     = (ushort*)(ws + 1*MB);   // [2048][1024]
  ushort* swgT   = (ushort*)(ws + 5*MB);
  ushort* swuT   = (ushort*)(ws + 7*MB);
  ushort* swdT   = (ushort*)(ws + 9*MB);
  ushort* wgT    = (ushort*)(ws + 11*MB);  // [16][512][1024]
  ushort* wuT    = (ushort*)(ws + 27*MB);
  ushort* wdT    = (ushort*)(ws + 43*MB);  // [16][1024][512]
  ushort* i_s    = (ushort*)(ws + 59*MB);  // [2048][1024]
  ushort* i_r    = (ushort*)(ws + 63*MB);  // [8192][512]
  ushort* y_r    = (ushort*)(ws + 11*MB);  // overlay wgT (dead after k_mm0) [8192][1024]
  ushort* y_s    = (ushort*)(ws + 27*MB);  // overlay wuT [2048][1024]

  hipMemsetAsync(counts, 0, 16 * CSTR * sizeof(int), stream);
  k_route<<<128, 256, 0, stream>>>(x, gk, gb, counts, tidx, tw);
  k_scan<<<1, 64, 0, stream>>>(counts, offs, cursor);
  k_place<<<NTOKS/256, 256, 0, stream>>>(tidx, tw, offs, cursor, tlist, wlist, pos);

  k_cvt<<<1024, 256, 0, stream>>>(x, xb, 262144);
  k_tr<<<dim3(16,16, 1), 256, 0, stream>>>(swg, swgT, 1024, 1024);
  k_tr<<<dim3(16,16, 1), 256, 0, stream>>>(swu, swuT, 1024, 1024);
  k_tr<<<dim3(16,16, 1), 256, 0, stream>>>(swd, swdT, 1024, 1024);
  k_tr<<<dim3( 8,16,16), 256, 0, stream>>>(wg,  wgT,  1024,  512);
  k_tr<<<dim3( 8,16,16), 256, 0, stream>>>(wu,  wuT,  1024,  512);
  k_tr<<<dim3(16, 8,16), 256, 0, stream>>>(wd,  wdT,   512, 1024);

  k_mm0<<<dim3(8,16,17), 512, 0, stream>>>(xb, i_s, i_r, swgT, swuT, wgT, wuT,
                                           counts, offs, tlist);
  k_mm1<<<dim3(8,8,17), 512, 0, stream>>>(i_s, i_r, swdT, wdT, y_s, y_r,
                                          counts, offs, wlist);
  k_comb<<<NTOKS/2, 256, 0, stream>>>(y_s, y_r, pos, out);
}